// Round 1
// baseline (52.737 us; speedup 1.0000x reference)
//
#include <hip/hip_runtime.h>

#define BB 64
#define TT 32
#define VV 50257

// Kernel 1: one block per (b,t) row. Online softmax (m, s) over V, then the 32
// label-position probabilities p = exp(x[l]-m)/s accumulated into agg_lab[b][t'].
__global__ __launch_bounds__(256) void row_softmax_agg(
    const float* __restrict__ logits,   // [B,T,V]
    const int*   __restrict__ labels,   // [B,T]
    const int*   __restrict__ lens,     // [B]
    float*       __restrict__ agg_lab)  // [B,T] accumulators (zeroed)
{
    const int bt = blockIdx.x;
    const int b  = bt >> 5;        // / TT
    const int t  = bt & (TT - 1);  // % TT
    if (t >= lens[b]) return;      // masked-out row: contributes nothing

    const float* row = logits + (size_t)bt * VV;
    const int tid = threadIdx.x;

    float m = -INFINITY;
    float s = 0.0f;

    // peel to 16B alignment (rows are only 4B-aligned: V*4 mod 16 == 4)
    const uintptr_t addr = (uintptr_t)row;
    const int head = (int)(((16u - (unsigned)(addr & 15)) & 15u) >> 2); // 0..3
    const float4* row4 = (const float4*)(row + head);
    const int nvec = (VV - head) >> 2;
    const int tail_start = head + (nvec << 2);

    // head scalars
    for (int i = tid; i < head; i += 256) {
        float xv = row[i];
        if (xv > m) { s = s * __expf(m - xv) + 1.0f; m = xv; }
        else        { s += __expf(xv - m); }
    }
    // vector body
    for (int i = tid; i < nvec; i += 256) {
        float4 x = row4[i];
        float xs[4] = {x.x, x.y, x.z, x.w};
        #pragma unroll
        for (int j = 0; j < 4; ++j) {
            float xv = xs[j];
            if (xv > m) { s = s * __expf(m - xv) + 1.0f; m = xv; }
            else        { s += __expf(xv - m); }
        }
    }
    // tail scalars
    for (int i = tail_start + tid; i < VV; i += 256) {
        float xv = row[i];
        if (xv > m) { s = s * __expf(m - xv) + 1.0f; m = xv; }
        else        { s += __expf(xv - m); }
    }

    // wave-level (64-lane) combine of (m, s)
    #pragma unroll
    for (int off = 32; off >= 1; off >>= 1) {
        float m2 = __shfl_xor(m, off);
        float s2 = __shfl_xor(s, off);
        float mn = fmaxf(m, m2);
        s = s * __expf(m - mn) + s2 * __expf(m2 - mn);
        m = mn;
    }

    // cross-wave combine via LDS (4 waves)
    __shared__ float m_sh[4], s_sh[4];
    __shared__ float mf, sf;
    const int wave = tid >> 6;
    const int lane = tid & 63;
    if (lane == 0) { m_sh[wave] = m; s_sh[wave] = s; }
    __syncthreads();
    if (tid == 0) {
        float M = m_sh[0], S = s_sh[0];
        #pragma unroll
        for (int w = 1; w < 4; ++w) {
            float mn = fmaxf(M, m_sh[w]);
            S = S * __expf(M - mn) + s_sh[w] * __expf(m_sh[w] - mn);
            M = mn;
        }
        mf = M; sf = S;
    }
    __syncthreads();
    const float M = mf;
    const float Sinv = 1.0f / sf;

    // 32 label gathers; row data is L2-resident right after the stream
    if (tid < TT) {
        const int l = labels[b * TT + tid];
        const float p = __expf(row[l] - M) * Sinv;
        atomicAdd(&agg_lab[b * TT + tid], p);
    }
}

// Kernel 2: per-sample loss terms + scalar reduction.
__global__ __launch_bounds__(64) void loss_reduce(
    const int*   __restrict__ labels,   // [B,T]
    const float* __restrict__ agg_lab,  // [B,T]
    float*       __restrict__ out)      // [1]
{
    const int b   = blockIdx.x;
    const int tid = threadIdx.x;
    float cov = 0.0f, rep = 0.0f, cnt = 0.0f;
    if (tid < TT) {
        const int l = labels[b * TT + tid];
        if (l > 2) {
            const float a = agg_lab[b * TT + tid];
            // -log(sigmoid(a)) = log1p(exp(-a))  (accurate for small a)
            cov = log1pf(__expf(-a));
            const float d = 1.0f - a;
            rep = d * d;
            cnt = 1.0f;
        }
    }
    #pragma unroll
    for (int off = 32; off >= 1; off >>= 1) {
        cov += __shfl_xor(cov, off);
        rep += __shfl_xor(rep, off);
        cnt += __shfl_xor(cnt, off);
    }
    if (tid == 0) {
        atomicAdd(out, (cov + rep) / cnt * (1.0f / BB));
    }
}

extern "C" void kernel_launch(void* const* d_in, const int* in_sizes, int n_in,
                              void* d_out, int out_size, void* d_ws, size_t ws_size,
                              hipStream_t stream) {
    const float* logits = (const float*)d_in[0];
    const int*   labels = (const int*)d_in[1];
    const int*   lens   = (const int*)d_in[2];
    float* out = (float*)d_out;
    float* agg = (float*)d_ws;   // B*T floats = 8 KB

    hipMemsetAsync(agg, 0, BB * TT * sizeof(float), stream);
    hipMemsetAsync(out, 0, sizeof(float), stream);

    row_softmax_agg<<<BB * TT, 256, 0, stream>>>(logits, labels, lens, agg);
    loss_reduce<<<BB, 64, 0, stream>>>(labels, agg, out);
}